// Round 6
// baseline (93.217 us; speedup 1.0000x reference)
//
#include <hip/hip_runtime.h>
#include <stdint.h>

// GCLSTM (single step, H=C=0) + MLP head, bf16 MFMA, fp32 accum/activations.
// Transposed formulation: G^T = W^T @ X^T, C-frags hold (col=node, row=feat).
// R6 changes vs R5 (trans ops measured ~1/8-rate => eliminate them):
//  - All sigmoid/tanh via Pade[5/4]: tanh(x) ~= x(945+105y+y^2)/(945+420y+15y^2),
//    y=x^2 (err <1e-5 for |x|<=1.6; inputs clamped to +-3). sigma(a) uses tanh(a/2)
//    with the /2 folded into the weight/bias tables.
//  - Rational algebra keeps everything as num/den products; ONE rcp per product,
//    batched across the 4 accumulator elements (rcp of product + prefix/suffix
//    recovery): 0.5 trans/elem total (was 6: 4 exp2 + 2 rcp).
//  - c = (d_u+u*n_u)(v*n_v)/(2 d_u d_v); h = (d_w+w*n_w)(c*n_c)/(2 d_w d_c).

typedef __attribute__((ext_vector_type(8))) short bf16x8;   // 8 bf16 = 4 VGPR
typedef __attribute__((ext_vector_type(4))) float f32x4;

constexpr int IN_F = 16;
constexpr int HID  = 128;
constexpr int MH1  = 64;
constexpr int MH2  = 32;
constexpr int WAVES = 8;
constexpr int ITER  = 2;                        // tiles per wave per block
constexpr int TILES_PER_BLOCK = WAVES * ITER;   // 16

// ---- LDS byte offsets ----
constexpr int GATE_F = 0;                   // 24 tiles * 512 B (lanes 0..31 real)
constexpr int M1_F   = 12288;               // 16 tiles * 1024 B
constexpr int M2_F   = 28672;               // 4 tiles * 1024 B
constexpr int BIAS_O = 32768;               // 3*128 f32 (scaled, hid-permuted)
constexpr int WCO_O  = 34304;               // 128 f32 (w_co/2, hid-permuted)
constexpr int M3_O   = 34816;               // 32 f32
constexpr int BM1_O  = 34944;               // 64 f32 (m1-permuted)
constexpr int BM2_O  = 35200;               // 32 f32
constexpr int BM3_O  = 35328;               // 1 f32
constexpr int LDS_BYTES = 35392;            // -> 4 blocks/CU

__device__ __forceinline__ short f2bf(float f) {   // RNE float->bf16 (init only)
    uint32_t u = __builtin_bit_cast(uint32_t, f);
    u += 0x7fffu + ((u >> 16) & 1u);
    return (short)(u >> 16);
}
__device__ __forceinline__ uint32_t cvt_pk(float lo, float hi) {  // bf16(lo)|bf16(hi)<<16
    uint32_t r;
    asm("v_cvt_pk_bf16_f32 %0, %1, %2" : "=v"(r) : "v"(lo), "v"(hi));
    return r;
}
// row permutation: tile mt (0..T-1), row r (0..15) -> feature index
__device__ __forceinline__ int permrow(int mt, int r) {
    return ((mt >> 1) << 5) + ((r >> 2) << 3) + ((mt & 1) << 2) + (r & 3);
}
__device__ __forceinline__ float clamp3(float x) {
    return fmaxf(fminf(x, 3.0f), -3.0f);
}
// Pade[5/4] tanh pieces: tanh(x) = x*n/d, y=x^2
__device__ __forceinline__ void pade_nd(float x, float& nn, float& dd) {
    float y = x * x;
    nn = fmaf(y, y + 105.0f, 945.0f);
    dd = fmaf(y, fmaf(y, 15.0f, 420.0f), 945.0f);
}

__global__ __launch_bounds__(512, 8) void gclstm_mfma_kernel(
    const float* __restrict__ x,
    const float* __restrict__ W_i, const float* __restrict__ W_c, const float* __restrict__ W_o,
    const float* __restrict__ bc_i, const float* __restrict__ bc_c, const float* __restrict__ bc_o,
    const float* __restrict__ w_co,
    const float* __restrict__ b_i, const float* __restrict__ b_c, const float* __restrict__ b_o,
    const float* __restrict__ M1, const float* __restrict__ bm1,
    const float* __restrict__ M2, const float* __restrict__ bm2,
    const float* __restrict__ M3, const float* __restrict__ bm3,
    float* __restrict__ out, int n)
{
    __shared__ __align__(16) char lds[LDS_BYTES];
    const int tid  = threadIdx.x;
    const int wid  = tid >> 6;
    const int lane = tid & 63;
    const int g    = lane >> 4;     // lane group 0..3
    const int ln   = lane & 15;

    // ---------------- init: build scaled, row-permuted bf16 fragment tables ----
    if (lane < 32) {
        for (int t = wid; t < 24; t += WAVES) {
            const int gi = t >> 3, mt = t & 7;
            const float* Wg = (gi == 0) ? W_i : (gi == 1) ? W_c : W_o;
            const float sc  = (gi == 1) ? 1.0f : 0.5f;   // /2 folded for sigmoid gates
            const int row = permrow(mt, ln);  // permuted hid index
            const int k0  = g * 8;            // input-feature index (g in 0..1)
            bf16x8 v;
            #pragma unroll
            for (int j = 0; j < 8; ++j) v[j] = f2bf(Wg[(k0 + j) * HID + row] * sc);
            *(bf16x8*)(lds + GATE_F + t * 512 + lane * 16) = v;
        }
    }
    // M1^T frags: A[r][k] = M1[k*64 + permrow(mt1, r)]; K(hid) natural order.
    for (int t = wid; t < 16; t += WAVES) {
        const int mt = t >> 2, kt = t & 3;
        const int row = permrow(mt, ln);      // permuted m1 index (mt in 0..3)
        const int k0  = kt * 32 + g * 8;
        bf16x8 v;
        #pragma unroll
        for (int j = 0; j < 8; ++j) v[j] = f2bf(M1[(k0 + j) * MH1 + row]);
        *(bf16x8*)(lds + M1_F + t * 1024 + lane * 16) = v;
    }
    // M2^T frags: A[r][k] = M2[k*32 + (mt2*16+r)]; K(m1) natural; rows natural.
    for (int t = wid; t < 4; t += WAVES) {
        const int mt = t >> 1, kt = t & 1;
        const int row = mt * 16 + ln;
        const int k0  = kt * 32 + g * 8;
        bf16x8 v;
        #pragma unroll
        for (int j = 0; j < 8; ++j) v[j] = f2bf(M2[(k0 + j) * MH2 + row]);
        *(bf16x8*)(lds + M2_F + t * 1024 + lane * 16) = v;
    }
    {
        float* biasS = (float*)(lds + BIAS_O);
        if (tid < HID) {
            const int h = permrow(tid >> 4, tid & 15);    // hid perm, mt in 0..7
            biasS[tid]           = (bc_i[h] + b_i[h]) * 0.5f;
            biasS[HID + tid]     = (bc_c[h] + b_c[h]);
            biasS[2 * HID + tid] = (bc_o[h] + b_o[h]) * 0.5f;
            ((float*)(lds + WCO_O))[tid] = 0.5f * w_co[h];
        }
        if (tid < MH1) {
            const int m = permrow(tid >> 4, tid & 15);    // m1 perm, mt in 0..3
            ((float*)(lds + BM1_O))[tid] = bm1[m];
        }
        if (tid < MH2) { ((float*)(lds + M3_O))[tid]  = M3[tid];
                         ((float*)(lds + BM2_O))[tid] = bm2[tid]; }
        if (tid == 0)  ((float*)(lds + BM3_O))[0] = bm3[0];
    }
    __syncthreads();

    const float* biasI = (const float*)(lds + BIAS_O);
    const float* biasC = biasI + HID;
    const float* biasO = biasC + HID;
    const float* wcoS  = (const float*)(lds + WCO_O);
    const float* m3S   = (const float*)(lds + M3_O);
    const float* bm1S  = (const float*)(lds + BM1_O);
    const float* bm2S  = (const float*)(lds + BM2_O);
    const float  bm3v  = ((const float*)(lds + BM3_O))[0];

    for (int it = 0; it < ITER; ++it) {
        const long tileIdx = (long)blockIdx.x * TILES_PER_BLOCK + it * WAVES + wid;
        const long base = tileIdx * 16;
        if (base >= n) break;

        // x B-frag: lane holds col=node(ln), k=g*8+j; k>=16 -> 0.
        bf16x8 xf;
        #pragma unroll
        for (int j = 0; j < 8; ++j) xf[j] = 0;
        if (g < 2) {
            const float* xp = x + (base + ln) * IN_F + g * 8;
            float4 a = *(const float4*)xp;
            float4 b = *(const float4*)(xp + 4);
            union { uint32_t u[4]; bf16x8 v; } cv;
            cv.u[0] = cvt_pk(a.x, a.y); cv.u[1] = cvt_pk(a.z, a.w);
            cv.u[2] = cvt_pk(b.x, b.y); cv.u[3] = cvt_pk(b.z, b.w);
            xf = cv.v;
        }

        // ---- gates + activations; hpk holds packed H (permuted rows -> B-frags).
        uint32_t hpk[16];
        #pragma unroll
        for (int mt = 0; mt < 8; ++mt) {
            const int h0 = mt * 16 + g * 4;             // permuted-bias position
            bf16x8 fi = *(const bf16x8*)(lds + GATE_F + (0 * 8 + mt) * 512 + (lane & 31) * 16);
            bf16x8 fc = *(const bf16x8*)(lds + GATE_F + (1 * 8 + mt) * 512 + (lane & 31) * 16);
            bf16x8 fo = *(const bf16x8*)(lds + GATE_F + (2 * 8 + mt) * 512 + (lane & 31) * 16);
            f32x4 bI = *(const f32x4*)(biasI + h0);
            f32x4 bC = *(const f32x4*)(biasC + h0);
            f32x4 bO = *(const f32x4*)(biasO + h0);
            // ai = a_i/2 ; ac = a_c ; ao = a_o/2 (pre-peephole)
            f32x4 ai = __builtin_amdgcn_mfma_f32_16x16x32_bf16(fi, xf, bI, 0, 0, 0);
            f32x4 ac = __builtin_amdgcn_mfma_f32_16x16x32_bf16(fc, xf, bC, 0, 0, 0);
            f32x4 ao = __builtin_amdgcn_mfma_f32_16x16x32_bf16(fo, xf, bO, 0, 0, 0);
            f32x4 wc = *(const f32x4*)(wcoS + h0);      // w_co/2

            // Stage A: c = sigma(2u)*tanh(v) = (d_u+u n_u)(v n_v) / (2 d_u d_v)
            float numc[4], Dc[4];
            #pragma unroll
            for (int i = 0; i < 4; ++i) {
                float u = clamp3(ai[i]);
                float v = clamp3(ac[i]);
                float nu, du, nv, dv;
                pade_nd(u, nu, du);
                pade_nd(v, nv, dv);
                numc[i] = fmaf(u, nu, du) * (v * nv);
                Dc[i]   = du * dv;
            }
            float Pc01 = Dc[0] * Dc[1], Pc23 = Dc[2] * Dc[3];
            float Pc   = Pc01 * Pc23;
            float Rc   = __builtin_amdgcn_rcpf(Pc + Pc);     // 1/(2*prod)
            float Rc01 = Rc * Pc23, Rc23 = Rc * Pc01;
            float cN[4];
            cN[0] = numc[0] * (Rc01 * Dc[1]);
            cN[1] = numc[1] * (Rc01 * Dc[0]);
            cN[2] = numc[2] * (Rc23 * Dc[3]);
            cN[3] = numc[3] * (Rc23 * Dc[2]);

            // Stage B: h = sigma(2w)*tanh(c) = (d_w+w n_w)(c n_c) / (2 d_w d_c)
            float numh[4], Dh[4];
            #pragma unroll
            for (int i = 0; i < 4; ++i) {
                float c = cN[i];
                float w = fmaf(wc[i], c, ao[i]);        // (a_o + w_co*c)/2
                float nc, dc, nw, dw;
                pade_nd(c, nc, dc);
                pade_nd(w, nw, dw);
                numh[i] = fmaf(w, nw, dw) * (c * nc);
                Dh[i]   = dc * dw;
            }
            float Ph01 = Dh[0] * Dh[1], Ph23 = Dh[2] * Dh[3];
            float Ph   = Ph01 * Ph23;
            float Rh   = __builtin_amdgcn_rcpf(Ph + Ph);
            float Rh01 = Rh * Ph23, Rh23 = Rh * Ph01;
            float hv[4];
            hv[0] = fmaxf(numh[0] * (Rh01 * Dh[1]), 0.0f);
            hv[1] = fmaxf(numh[1] * (Rh01 * Dh[0]), 0.0f);
            hv[2] = fmaxf(numh[2] * (Rh23 * Dh[3]), 0.0f);
            hv[3] = fmaxf(numh[3] * (Rh23 * Dh[2]), 0.0f);

            hpk[mt * 2]     = cvt_pk(hv[0], hv[1]);
            hpk[mt * 2 + 1] = cvt_pk(hv[2], hv[3]);
        }

        // ---- MLP1: m1^T = M1^T @ H^T ; B-frag(kt) = hpk[4kt..4kt+3] ----
        uint32_t mpk[8];
        #pragma unroll
        for (int mt = 0; mt < 4; ++mt) {
            const int r0 = mt * 16 + g * 4;             // permuted-bias position
            f32x4 acc = *(const f32x4*)(bm1S + r0);     // bias as C-init
            #pragma unroll
            for (int kt = 0; kt < 4; ++kt) {
                union { uint32_t u[4]; bf16x8 v; } b;
                b.u[0] = hpk[4 * kt + 0]; b.u[1] = hpk[4 * kt + 1];
                b.u[2] = hpk[4 * kt + 2]; b.u[3] = hpk[4 * kt + 3];
                acc = __builtin_amdgcn_mfma_f32_16x16x32_bf16(
                    *(const bf16x8*)(lds + M1_F + (mt * 4 + kt) * 1024 + lane * 16), b.v, acc, 0, 0, 0);
            }
            float mv[4];
            #pragma unroll
            for (int i = 0; i < 4; ++i) mv[i] = fmaxf(acc[i], 0.f);
            mpk[mt * 2]     = cvt_pk(mv[0], mv[1]);
            mpk[mt * 2 + 1] = cvt_pk(mv[2], mv[3]);
        }

        // ---- MLP2 [32x64] + MLP3 dot; B-frag(kt2) = mpk[4kt2..4kt2+3] ----
        float outacc = 0.f;
        #pragma unroll
        for (int mt = 0; mt < 2; ++mt) {
            const int r0 = mt * 16 + g * 4;             // m2 index (natural)
            f32x4 acc = *(const f32x4*)(bm2S + r0);     // bias as C-init
            #pragma unroll
            for (int kt = 0; kt < 2; ++kt) {
                union { uint32_t u[4]; bf16x8 v; } b;
                b.u[0] = mpk[4 * kt + 0]; b.u[1] = mpk[4 * kt + 1];
                b.u[2] = mpk[4 * kt + 2]; b.u[3] = mpk[4 * kt + 3];
                acc = __builtin_amdgcn_mfma_f32_16x16x32_bf16(
                    *(const bf16x8*)(lds + M2_F + (mt * 2 + kt) * 1024 + lane * 16), b.v, acc, 0, 0, 0);
            }
            f32x4 w3 = *(const f32x4*)(m3S + r0);
            #pragma unroll
            for (int i = 0; i < 4; ++i)
                outacc = fmaf(fmaxf(acc[i], 0.f), w3[i], outacc);
        }
        outacc += __shfl_xor(outacc, 16);
        outacc += __shfl_xor(outacc, 32);
        if (lane < 16) out[base + lane] = outacc + bm3v;
    }
}

extern "C" void kernel_launch(void* const* d_in, const int* in_sizes, int n_in,
                              void* d_out, int out_size, void* d_ws, size_t ws_size,
                              hipStream_t stream) {
    const float* x    = (const float*)d_in[0];
    // d_in[1] edge_index, d_in[2] edge_weight: dead (ChebConv K=1 on H=0)
    const float* W_i  = (const float*)d_in[3];
    // d_in[4] W_f: dead (multiplies C=0)
    const float* W_c  = (const float*)d_in[5];
    const float* W_o  = (const float*)d_in[6];
    // d_in[7..10] Uc_*: dead (H=0)
    const float* bc_i = (const float*)d_in[11];
    const float* bc_c = (const float*)d_in[13];
    const float* bc_o = (const float*)d_in[14];
    const float* w_co = (const float*)d_in[17];
    const float* b_i  = (const float*)d_in[18];
    const float* b_c  = (const float*)d_in[20];
    const float* b_o  = (const float*)d_in[21];
    const float* M1   = (const float*)d_in[22];
    const float* bm1  = (const float*)d_in[23];
    const float* M2   = (const float*)d_in[24];
    const float* bm2  = (const float*)d_in[25];
    const float* M3   = (const float*)d_in[26];
    const float* bm3  = (const float*)d_in[27];
    float* out = (float*)d_out;

    const int n = in_sizes[0] / IN_F;                   // 500000
    const int tiles = (n + 15) / 16;                    // 31250
    const int grid = (tiles + TILES_PER_BLOCK - 1) / TILES_PER_BLOCK;

    gclstm_mfma_kernel<<<grid, 512, 0, stream>>>(
        x, W_i, W_c, W_o, bc_i, bc_c, bc_o, w_co,
        b_i, b_c, b_o, M1, bm1, M2, bm2, M3, bm3, out, n);
}

// Round 7
// 64.484 us; speedup vs baseline: 1.4456x; 1.4456x over previous
//
#include <hip/hip_runtime.h>
#include <stdint.h>

// GCLSTM (single step, H=C=0) + MLP head, bf16 MFMA, fp32 accum/activations.
// Transposed formulation: G^T = W^T @ X^T, C-frags hold (col=node, row=feat).
// R7 changes (revert R6's Pade; back to R5's exp2 activations):
//  - Co-resident grid: ITER=4 -> 977 blocks <= 1024 resident slots (4 blocks/CU
//    x 256 CU); no second dispatch round, occupancy ramp eliminated.
//  - rcp batched 4-wide across accumulator elements (rcp of product + recovery):
//    3 trans -> 1 per 4 elems per stage; exp2 gates kept (trans ~16cyc = cheaper
//    than any poly at >8 VALU ops; R6 proved the full-Pade path regresses).

typedef __attribute__((ext_vector_type(8))) short bf16x8;   // 8 bf16 = 4 VGPR
typedef __attribute__((ext_vector_type(4))) float f32x4;

constexpr int IN_F = 16;
constexpr int HID  = 128;
constexpr int MH1  = 64;
constexpr int MH2  = 32;
constexpr int WAVES = 8;
constexpr int ITER  = 4;                        // tiles per wave per block
constexpr int TILES_PER_BLOCK = WAVES * ITER;   // 32

constexpr float LOG2E = 1.4426950408889634f;
constexpr float TWO_L = 2.8853900817779268f;

// ---- LDS byte offsets ----
constexpr int GATE_F = 0;                   // 24 tiles * 512 B (lanes 0..31 real)
constexpr int M1_F   = 12288;               // 16 tiles * 1024 B
constexpr int M2_F   = 28672;               // 4 tiles * 1024 B
constexpr int BIAS_O = 32768;               // 3*128 f32 (scaled, hid-permuted)
constexpr int WCO_O  = 34304;               // 128 f32 (-w_co/2, hid-permuted)
constexpr int M3_O   = 34816;               // 32 f32
constexpr int BM1_O  = 34944;               // 64 f32 (m1-permuted)
constexpr int BM2_O  = 35200;               // 32 f32
constexpr int BM3_O  = 35328;               // 1 f32
constexpr int LDS_BYTES = 35392;            // -> 4 blocks/CU

__device__ __forceinline__ short f2bf(float f) {   // RNE float->bf16 (init only)
    uint32_t u = __builtin_bit_cast(uint32_t, f);
    u += 0x7fffu + ((u >> 16) & 1u);
    return (short)(u >> 16);
}
__device__ __forceinline__ uint32_t cvt_pk(float lo, float hi) {  // bf16(lo)|bf16(hi)<<16
    uint32_t r;
    asm("v_cvt_pk_bf16_f32 %0, %1, %2" : "=v"(r) : "v"(lo), "v"(hi));
    return r;
}
// row permutation: tile mt (0..T-1), row r (0..15) -> feature index
__device__ __forceinline__ int permrow(int mt, int r) {
    return ((mt >> 1) << 5) + ((r >> 2) << 3) + ((mt & 1) << 2) + (r & 3);
}

__global__ __launch_bounds__(512, 8) void gclstm_mfma_kernel(
    const float* __restrict__ x,
    const float* __restrict__ W_i, const float* __restrict__ W_c, const float* __restrict__ W_o,
    const float* __restrict__ bc_i, const float* __restrict__ bc_c, const float* __restrict__ bc_o,
    const float* __restrict__ w_co,
    const float* __restrict__ b_i, const float* __restrict__ b_c, const float* __restrict__ b_o,
    const float* __restrict__ M1, const float* __restrict__ bm1,
    const float* __restrict__ M2, const float* __restrict__ bm2,
    const float* __restrict__ M3, const float* __restrict__ bm3,
    float* __restrict__ out, int n)
{
    __shared__ __align__(16) char lds[LDS_BYTES];
    const int tid  = threadIdx.x;
    const int wid  = tid >> 6;
    const int lane = tid & 63;
    const int g    = lane >> 4;     // lane group 0..3
    const int ln   = lane & 15;

    // ---------------- init: build scaled, row-permuted bf16 fragment tables ----
    if (lane < 32) {
        for (int t = wid; t < 24; t += WAVES) {
            const int gi = t >> 3, mt = t & 7;
            const float* Wg = (gi == 0) ? W_i : (gi == 1) ? W_c : W_o;
            const float sc  = (gi == 1) ? TWO_L : -LOG2E;
            const int row = permrow(mt, ln);  // permuted hid index
            const int k0  = g * 8;            // input-feature index (g in 0..1)
            bf16x8 v;
            #pragma unroll
            for (int j = 0; j < 8; ++j) v[j] = f2bf(Wg[(k0 + j) * HID + row] * sc);
            *(bf16x8*)(lds + GATE_F + t * 512 + lane * 16) = v;
        }
    }
    // M1^T frags: A[r][k] = M1[k*64 + permrow(mt1, r)]; K(hid) natural order.
    for (int t = wid; t < 16; t += WAVES) {
        const int mt = t >> 2, kt = t & 3;
        const int row = permrow(mt, ln);      // permuted m1 index (mt in 0..3)
        const int k0  = kt * 32 + g * 8;
        bf16x8 v;
        #pragma unroll
        for (int j = 0; j < 8; ++j) v[j] = f2bf(M1[(k0 + j) * MH1 + row]);
        *(bf16x8*)(lds + M1_F + t * 1024 + lane * 16) = v;
    }
    // M2^T frags: A[r][k] = M2[k*32 + (mt2*16+r)]; K(m1) natural; rows natural.
    for (int t = wid; t < 4; t += WAVES) {
        const int mt = t >> 1, kt = t & 1;
        const int row = mt * 16 + ln;
        const int k0  = kt * 32 + g * 8;
        bf16x8 v;
        #pragma unroll
        for (int j = 0; j < 8; ++j) v[j] = f2bf(M2[(k0 + j) * MH2 + row]);
        *(bf16x8*)(lds + M2_F + t * 1024 + lane * 16) = v;
    }
    {
        float* biasS = (float*)(lds + BIAS_O);
        if (tid < HID) {
            const int h = permrow(tid >> 4, tid & 15);    // hid perm, mt in 0..7
            biasS[tid]           = (bc_i[h] + b_i[h]) * (-LOG2E);
            biasS[HID + tid]     = (bc_c[h] + b_c[h]) * TWO_L;
            biasS[2 * HID + tid] = (bc_o[h] + b_o[h]) * (-LOG2E);
            ((float*)(lds + WCO_O))[tid] = -0.5f * w_co[h];
        }
        if (tid < MH1) {
            const int m = permrow(tid >> 4, tid & 15);    // m1 perm, mt in 0..3
            ((float*)(lds + BM1_O))[tid] = bm1[m];
        }
        if (tid < MH2) { ((float*)(lds + M3_O))[tid]  = M3[tid];
                         ((float*)(lds + BM2_O))[tid] = bm2[tid]; }
        if (tid == 0)  ((float*)(lds + BM3_O))[0] = bm3[0];
    }
    __syncthreads();

    const float* biasI = (const float*)(lds + BIAS_O);
    const float* biasC = biasI + HID;
    const float* biasO = biasC + HID;
    const float* wcoS  = (const float*)(lds + WCO_O);
    const float* m3S   = (const float*)(lds + M3_O);
    const float* bm1S  = (const float*)(lds + BM1_O);
    const float* bm2S  = (const float*)(lds + BM2_O);
    const float  bm3v  = ((const float*)(lds + BM3_O))[0];

    for (int it = 0; it < ITER; ++it) {
        const long tileIdx = (long)blockIdx.x * TILES_PER_BLOCK + it * WAVES + wid;
        const long base = tileIdx * 16;
        if (base >= n) break;

        // x B-frag: lane holds col=node(ln), k=g*8+j; k>=16 -> 0.
        bf16x8 xf;
        #pragma unroll
        for (int j = 0; j < 8; ++j) xf[j] = 0;
        if (g < 2) {
            const float* xp = x + (base + ln) * IN_F + g * 8;
            float4 a = *(const float4*)xp;
            float4 b = *(const float4*)(xp + 4);
            union { uint32_t u[4]; bf16x8 v; } cv;
            cv.u[0] = cvt_pk(a.x, a.y); cv.u[1] = cvt_pk(a.z, a.w);
            cv.u[2] = cvt_pk(b.x, b.y); cv.u[3] = cvt_pk(b.z, b.w);
            xf = cv.v;
        }

        // ---- gates + activations; hpk holds packed H (permuted rows -> B-frags).
        uint32_t hpk[16];
        #pragma unroll
        for (int mt = 0; mt < 8; ++mt) {
            const int h0 = mt * 16 + g * 4;             // permuted-bias position
            bf16x8 fi = *(const bf16x8*)(lds + GATE_F + (0 * 8 + mt) * 512 + (lane & 31) * 16);
            bf16x8 fc = *(const bf16x8*)(lds + GATE_F + (1 * 8 + mt) * 512 + (lane & 31) * 16);
            bf16x8 fo = *(const bf16x8*)(lds + GATE_F + (2 * 8 + mt) * 512 + (lane & 31) * 16);
            f32x4 bI = *(const f32x4*)(biasI + h0);
            f32x4 bC = *(const f32x4*)(biasC + h0);
            f32x4 bO = *(const f32x4*)(biasO + h0);
            // ai = -L*a_i ; ac = 2L*a_c ; ao = -L*(x@W_o+b_o)
            f32x4 ai = __builtin_amdgcn_mfma_f32_16x16x32_bf16(fi, xf, bI, 0, 0, 0);
            f32x4 ac = __builtin_amdgcn_mfma_f32_16x16x32_bf16(fc, xf, bC, 0, 0, 0);
            f32x4 ao = __builtin_amdgcn_mfma_f32_16x16x32_bf16(fo, xf, bO, 0, 0, 0);
            f32x4 wc = *(const f32x4*)(wcoS + h0);      // -w_co/2

            // Stage A: c = I*T = (Ec-1)/[(1+Ei)(Ec+1)]; cp = 2L*c.
            // One rcp per 4 elems: R = 1/(den0*den1*den2*den3), recover 1/den_i.
            float den[4], num[4];
            #pragma unroll
            for (int i = 0; i < 4; ++i) {
                float Ei = __builtin_amdgcn_exp2f(ai[i]);   // e^{-a_i}
                float Ec = __builtin_amdgcn_exp2f(ac[i]);   // e^{2 a_c}
                den[i] = (1.0f + Ei) * (Ec + 1.0f);
                num[i] = Ec - 1.0f;
            }
            float P01 = den[0] * den[1], P23 = den[2] * den[3];
            float R   = __builtin_amdgcn_rcpf(P01 * P23);
            float RL  = R * TWO_L;
            float t01 = RL * P23, t23 = RL * P01;
            float cp[4];
            cp[0] = num[0] * (t01 * den[1]);
            cp[1] = num[1] * (t01 * den[0]);
            cp[2] = num[2] * (t23 * den[3]);
            cp[3] = num[3] * (t23 * den[2]);

            // Stage B: h = O*tanh(c) = (E2-1)/[(1+Eo)(E2+1)], same batched rcp.
            float den2[4], num2[4];
            #pragma unroll
            for (int i = 0; i < 4; ++i) {
                float Eo = __builtin_amdgcn_exp2f(fmaf(wc[i], cp[i], ao[i])); // e^{-a_o'}
                float E2 = __builtin_amdgcn_exp2f(cp[i]);                     // e^{2c}
                den2[i] = (1.0f + Eo) * (E2 + 1.0f);
                num2[i] = E2 - 1.0f;
            }
            float Q01 = den2[0] * den2[1], Q23 = den2[2] * den2[3];
            float R2  = __builtin_amdgcn_rcpf(Q01 * Q23);
            float s01 = R2 * Q23, s23 = R2 * Q01;
            float hv[4];
            hv[0] = fmaxf(num2[0] * (s01 * den2[1]), 0.0f);
            hv[1] = fmaxf(num2[1] * (s01 * den2[0]), 0.0f);
            hv[2] = fmaxf(num2[2] * (s23 * den2[3]), 0.0f);
            hv[3] = fmaxf(num2[3] * (s23 * den2[2]), 0.0f);

            hpk[mt * 2]     = cvt_pk(hv[0], hv[1]);
            hpk[mt * 2 + 1] = cvt_pk(hv[2], hv[3]);
        }

        // ---- MLP1: m1^T = M1^T @ H^T ; B-frag(kt) = hpk[4kt..4kt+3] ----
        uint32_t mpk[8];
        #pragma unroll
        for (int mt = 0; mt < 4; ++mt) {
            const int r0 = mt * 16 + g * 4;             // permuted-bias position
            f32x4 acc = *(const f32x4*)(bm1S + r0);     // bias as C-init
            #pragma unroll
            for (int kt = 0; kt < 4; ++kt) {
                union { uint32_t u[4]; bf16x8 v; } b;
                b.u[0] = hpk[4 * kt + 0]; b.u[1] = hpk[4 * kt + 1];
                b.u[2] = hpk[4 * kt + 2]; b.u[3] = hpk[4 * kt + 3];
                acc = __builtin_amdgcn_mfma_f32_16x16x32_bf16(
                    *(const bf16x8*)(lds + M1_F + (mt * 4 + kt) * 1024 + lane * 16), b.v, acc, 0, 0, 0);
            }
            float mv[4];
            #pragma unroll
            for (int i = 0; i < 4; ++i) mv[i] = fmaxf(acc[i], 0.f);
            mpk[mt * 2]     = cvt_pk(mv[0], mv[1]);
            mpk[mt * 2 + 1] = cvt_pk(mv[2], mv[3]);
        }

        // ---- MLP2 [32x64] + MLP3 dot; B-frag(kt2) = mpk[4kt2..4kt2+3] ----
        float outacc = 0.f;
        #pragma unroll
        for (int mt = 0; mt < 2; ++mt) {
            const int r0 = mt * 16 + g * 4;             // m2 index (natural)
            f32x4 acc = *(const f32x4*)(bm2S + r0);     // bias as C-init
            #pragma unroll
            for (int kt = 0; kt < 2; ++kt) {
                union { uint32_t u[4]; bf16x8 v; } b;
                b.u[0] = mpk[4 * kt + 0]; b.u[1] = mpk[4 * kt + 1];
                b.u[2] = mpk[4 * kt + 2]; b.u[3] = mpk[4 * kt + 3];
                acc = __builtin_amdgcn_mfma_f32_16x16x32_bf16(
                    *(const bf16x8*)(lds + M2_F + (mt * 2 + kt) * 1024 + lane * 16), b.v, acc, 0, 0, 0);
            }
            f32x4 w3 = *(const f32x4*)(m3S + r0);
            #pragma unroll
            for (int i = 0; i < 4; ++i)
                outacc = fmaf(fmaxf(acc[i], 0.f), w3[i], outacc);
        }
        outacc += __shfl_xor(outacc, 16);
        outacc += __shfl_xor(outacc, 32);
        if (lane < 16) out[base + lane] = outacc + bm3v;
    }
}

extern "C" void kernel_launch(void* const* d_in, const int* in_sizes, int n_in,
                              void* d_out, int out_size, void* d_ws, size_t ws_size,
                              hipStream_t stream) {
    const float* x    = (const float*)d_in[0];
    // d_in[1] edge_index, d_in[2] edge_weight: dead (ChebConv K=1 on H=0)
    const float* W_i  = (const float*)d_in[3];
    // d_in[4] W_f: dead (multiplies C=0)
    const float* W_c  = (const float*)d_in[5];
    const float* W_o  = (const float*)d_in[6];
    // d_in[7..10] Uc_*: dead (H=0)
    const float* bc_i = (const float*)d_in[11];
    const float* bc_c = (const float*)d_in[13];
    const float* bc_o = (const float*)d_in[14];
    const float* w_co = (const float*)d_in[17];
    const float* b_i  = (const float*)d_in[18];
    const float* b_c  = (const float*)d_in[20];
    const float* b_o  = (const float*)d_in[21];
    const float* M1   = (const float*)d_in[22];
    const float* bm1  = (const float*)d_in[23];
    const float* M2   = (const float*)d_in[24];
    const float* bm2  = (const float*)d_in[25];
    const float* M3   = (const float*)d_in[26];
    const float* bm3  = (const float*)d_in[27];
    float* out = (float*)d_out;

    const int n = in_sizes[0] / IN_F;                   // 500000
    const int tiles = (n + 15) / 16;                    // 31250
    const int grid = (tiles + TILES_PER_BLOCK - 1) / TILES_PER_BLOCK;  // 977

    gclstm_mfma_kernel<<<grid, 512, 0, stream>>>(
        x, W_i, W_c, W_o, bc_i, bc_c, bc_o, w_co,
        b_i, b_c, b_o, M1, bm1, M2, bm2, M3, bm3, out, n);
}

// Round 8
// 63.991 us; speedup vs baseline: 1.4567x; 1.0077x over previous
//
#include <hip/hip_runtime.h>
#include <stdint.h>

// GCLSTM (single step, H=C=0) + MLP head, bf16 MFMA, fp32 accum/activations.
// Transposed formulation: G^T = W^T @ X^T, C-frags hold (col=node, row=feat).
// R8 changes vs R7 (residency model fix):
//  - Measured occupancies fit a 3-blocks/CU cap for 512-thread/35.8KB blocks
//    (R7 49% = 768 resident + idle 2nd round; R5 62% = 2.54 rounds).
//  - 1024-thread blocks (16 waves): wave cap 32/CU => exactly 2 blocks/CU
//    resident = 100% wave occupancy; LDS 2x35.8KB = 72KB fits any pool size.
//  - ITER=4 -> 64 tiles/block -> 489 blocks <= 512 slots: ONE co-resident
//    round, no idle tail.

typedef __attribute__((ext_vector_type(8))) short bf16x8;   // 8 bf16 = 4 VGPR
typedef __attribute__((ext_vector_type(4))) float f32x4;

constexpr int IN_F = 16;
constexpr int HID  = 128;
constexpr int MH1  = 64;
constexpr int MH2  = 32;
constexpr int WAVES = 16;
constexpr int ITER  = 4;                        // tiles per wave per block
constexpr int TILES_PER_BLOCK = WAVES * ITER;   // 64

constexpr float LOG2E = 1.4426950408889634f;
constexpr float TWO_L = 2.8853900817779268f;

// ---- LDS byte offsets ----
constexpr int GATE_F = 0;                   // 24 tiles * 512 B (lanes 0..31 real)
constexpr int M1_F   = 12288;               // 16 tiles * 1024 B
constexpr int M2_F   = 28672;               // 4 tiles * 1024 B
constexpr int BIAS_O = 32768;               // 3*128 f32 (scaled, hid-permuted)
constexpr int WCO_O  = 34304;               // 128 f32 (-w_co/2, hid-permuted)
constexpr int M3_O   = 34816;               // 32 f32
constexpr int BM1_O  = 34944;               // 64 f32 (m1-permuted)
constexpr int BM2_O  = 35200;               // 32 f32
constexpr int BM3_O  = 35328;               // 1 f32
constexpr int LDS_BYTES = 35392;            // 2 blocks/CU by wave cap

__device__ __forceinline__ short f2bf(float f) {   // RNE float->bf16 (init only)
    uint32_t u = __builtin_bit_cast(uint32_t, f);
    u += 0x7fffu + ((u >> 16) & 1u);
    return (short)(u >> 16);
}
__device__ __forceinline__ uint32_t cvt_pk(float lo, float hi) {  // bf16(lo)|bf16(hi)<<16
    uint32_t r;
    asm("v_cvt_pk_bf16_f32 %0, %1, %2" : "=v"(r) : "v"(lo), "v"(hi));
    return r;
}
// row permutation: tile mt (0..T-1), row r (0..15) -> feature index
__device__ __forceinline__ int permrow(int mt, int r) {
    return ((mt >> 1) << 5) + ((r >> 2) << 3) + ((mt & 1) << 2) + (r & 3);
}

__global__ __launch_bounds__(1024, 8) void gclstm_mfma_kernel(
    const float* __restrict__ x,
    const float* __restrict__ W_i, const float* __restrict__ W_c, const float* __restrict__ W_o,
    const float* __restrict__ bc_i, const float* __restrict__ bc_c, const float* __restrict__ bc_o,
    const float* __restrict__ w_co,
    const float* __restrict__ b_i, const float* __restrict__ b_c, const float* __restrict__ b_o,
    const float* __restrict__ M1, const float* __restrict__ bm1,
    const float* __restrict__ M2, const float* __restrict__ bm2,
    const float* __restrict__ M3, const float* __restrict__ bm3,
    float* __restrict__ out, int n)
{
    __shared__ __align__(16) char lds[LDS_BYTES];
    const int tid  = threadIdx.x;
    const int wid  = tid >> 6;
    const int lane = tid & 63;
    const int g    = lane >> 4;     // lane group 0..3
    const int ln   = lane & 15;

    // ---------------- init: build scaled, row-permuted bf16 fragment tables ----
    if (lane < 32) {
        for (int t = wid; t < 24; t += WAVES) {
            const int gi = t >> 3, mt = t & 7;
            const float* Wg = (gi == 0) ? W_i : (gi == 1) ? W_c : W_o;
            const float sc  = (gi == 1) ? TWO_L : -LOG2E;
            const int row = permrow(mt, ln);  // permuted hid index
            const int k0  = g * 8;            // input-feature index (g in 0..1)
            bf16x8 v;
            #pragma unroll
            for (int j = 0; j < 8; ++j) v[j] = f2bf(Wg[(k0 + j) * HID + row] * sc);
            *(bf16x8*)(lds + GATE_F + t * 512 + lane * 16) = v;
        }
    }
    // M1^T frags: A[r][k] = M1[k*64 + permrow(mt1, r)]; K(hid) natural order.
    for (int t = wid; t < 16; t += WAVES) {
        const int mt = t >> 2, kt = t & 3;
        const int row = permrow(mt, ln);      // permuted m1 index (mt in 0..3)
        const int k0  = kt * 32 + g * 8;
        bf16x8 v;
        #pragma unroll
        for (int j = 0; j < 8; ++j) v[j] = f2bf(M1[(k0 + j) * MH1 + row]);
        *(bf16x8*)(lds + M1_F + t * 1024 + lane * 16) = v;
    }
    // M2^T frags: A[r][k] = M2[k*32 + (mt2*16+r)]; K(m1) natural; rows natural.
    for (int t = wid; t < 4; t += WAVES) {
        const int mt = t >> 1, kt = t & 1;
        const int row = mt * 16 + ln;
        const int k0  = kt * 32 + g * 8;
        bf16x8 v;
        #pragma unroll
        for (int j = 0; j < 8; ++j) v[j] = f2bf(M2[(k0 + j) * MH2 + row]);
        *(bf16x8*)(lds + M2_F + t * 1024 + lane * 16) = v;
    }
    {
        float* biasS = (float*)(lds + BIAS_O);
        if (tid < HID) {
            const int h = permrow(tid >> 4, tid & 15);    // hid perm, mt in 0..7
            biasS[tid]           = (bc_i[h] + b_i[h]) * (-LOG2E);
            biasS[HID + tid]     = (bc_c[h] + b_c[h]) * TWO_L;
            biasS[2 * HID + tid] = (bc_o[h] + b_o[h]) * (-LOG2E);
            ((float*)(lds + WCO_O))[tid] = -0.5f * w_co[h];
        }
        if (tid < MH1) {
            const int m = permrow(tid >> 4, tid & 15);    // m1 perm, mt in 0..3
            ((float*)(lds + BM1_O))[tid] = bm1[m];
        }
        if (tid < MH2) { ((float*)(lds + M3_O))[tid]  = M3[tid];
                         ((float*)(lds + BM2_O))[tid] = bm2[tid]; }
        if (tid == 0)  ((float*)(lds + BM3_O))[0] = bm3[0];
    }
    __syncthreads();

    const float* biasI = (const float*)(lds + BIAS_O);
    const float* biasC = biasI + HID;
    const float* biasO = biasC + HID;
    const float* wcoS  = (const float*)(lds + WCO_O);
    const float* m3S   = (const float*)(lds + M3_O);
    const float* bm1S  = (const float*)(lds + BM1_O);
    const float* bm2S  = (const float*)(lds + BM2_O);
    const float  bm3v  = ((const float*)(lds + BM3_O))[0];

    for (int it = 0; it < ITER; ++it) {
        const long tileIdx = (long)blockIdx.x * TILES_PER_BLOCK + it * WAVES + wid;
        const long base = tileIdx * 16;
        if (base >= n) break;

        // x B-frag: lane holds col=node(ln), k=g*8+j; k>=16 -> 0.
        bf16x8 xf;
        #pragma unroll
        for (int j = 0; j < 8; ++j) xf[j] = 0;
        if (g < 2) {
            const float* xp = x + (base + ln) * IN_F + g * 8;
            float4 a = *(const float4*)xp;
            float4 b = *(const float4*)(xp + 4);
            union { uint32_t u[4]; bf16x8 v; } cv;
            cv.u[0] = cvt_pk(a.x, a.y); cv.u[1] = cvt_pk(a.z, a.w);
            cv.u[2] = cvt_pk(b.x, b.y); cv.u[3] = cvt_pk(b.z, b.w);
            xf = cv.v;
        }

        // ---- gates + activations; hpk holds packed H (permuted rows -> B-frags).
        uint32_t hpk[16];
        #pragma unroll
        for (int mt = 0; mt < 8; ++mt) {
            const int h0 = mt * 16 + g * 4;             // permuted-bias position
            bf16x8 fi = *(const bf16x8*)(lds + GATE_F + (0 * 8 + mt) * 512 + (lane & 31) * 16);
            bf16x8 fc = *(const bf16x8*)(lds + GATE_F + (1 * 8 + mt) * 512 + (lane & 31) * 16);
            bf16x8 fo = *(const bf16x8*)(lds + GATE_F + (2 * 8 + mt) * 512 + (lane & 31) * 16);
            f32x4 bI = *(const f32x4*)(biasI + h0);
            f32x4 bC = *(const f32x4*)(biasC + h0);
            f32x4 bO = *(const f32x4*)(biasO + h0);
            // ai = -L*a_i ; ac = 2L*a_c ; ao = -L*(x@W_o+b_o)
            f32x4 ai = __builtin_amdgcn_mfma_f32_16x16x32_bf16(fi, xf, bI, 0, 0, 0);
            f32x4 ac = __builtin_amdgcn_mfma_f32_16x16x32_bf16(fc, xf, bC, 0, 0, 0);
            f32x4 ao = __builtin_amdgcn_mfma_f32_16x16x32_bf16(fo, xf, bO, 0, 0, 0);
            f32x4 wc = *(const f32x4*)(wcoS + h0);      // -w_co/2

            // Stage A: c = I*T = (Ec-1)/[(1+Ei)(Ec+1)]; cp = 2L*c.
            float den[4], num[4];
            #pragma unroll
            for (int i = 0; i < 4; ++i) {
                float Ei = __builtin_amdgcn_exp2f(ai[i]);   // e^{-a_i}
                float Ec = __builtin_amdgcn_exp2f(ac[i]);   // e^{2 a_c}
                den[i] = (1.0f + Ei) * (Ec + 1.0f);
                num[i] = Ec - 1.0f;
            }
            float P01 = den[0] * den[1], P23 = den[2] * den[3];
            float R   = __builtin_amdgcn_rcpf(P01 * P23);
            float RL  = R * TWO_L;
            float t01 = RL * P23, t23 = RL * P01;
            float cp[4];
            cp[0] = num[0] * (t01 * den[1]);
            cp[1] = num[1] * (t01 * den[0]);
            cp[2] = num[2] * (t23 * den[3]);
            cp[3] = num[3] * (t23 * den[2]);

            // Stage B: h = O*tanh(c) = (E2-1)/[(1+Eo)(E2+1)], same batched rcp.
            float den2[4], num2[4];
            #pragma unroll
            for (int i = 0; i < 4; ++i) {
                float Eo = __builtin_amdgcn_exp2f(fmaf(wc[i], cp[i], ao[i])); // e^{-a_o'}
                float E2 = __builtin_amdgcn_exp2f(cp[i]);                     // e^{2c}
                den2[i] = (1.0f + Eo) * (E2 + 1.0f);
                num2[i] = E2 - 1.0f;
            }
            float Q01 = den2[0] * den2[1], Q23 = den2[2] * den2[3];
            float R2  = __builtin_amdgcn_rcpf(Q01 * Q23);
            float s01 = R2 * Q23, s23 = R2 * Q01;
            float hv[4];
            hv[0] = fmaxf(num2[0] * (s01 * den2[1]), 0.0f);
            hv[1] = fmaxf(num2[1] * (s01 * den2[0]), 0.0f);
            hv[2] = fmaxf(num2[2] * (s23 * den2[3]), 0.0f);
            hv[3] = fmaxf(num2[3] * (s23 * den2[2]), 0.0f);

            hpk[mt * 2]     = cvt_pk(hv[0], hv[1]);
            hpk[mt * 2 + 1] = cvt_pk(hv[2], hv[3]);
        }

        // ---- MLP1: m1^T = M1^T @ H^T ; B-frag(kt) = hpk[4kt..4kt+3] ----
        uint32_t mpk[8];
        #pragma unroll
        for (int mt = 0; mt < 4; ++mt) {
            const int r0 = mt * 16 + g * 4;             // permuted-bias position
            f32x4 acc = *(const f32x4*)(bm1S + r0);     // bias as C-init
            #pragma unroll
            for (int kt = 0; kt < 4; ++kt) {
                union { uint32_t u[4]; bf16x8 v; } b;
                b.u[0] = hpk[4 * kt + 0]; b.u[1] = hpk[4 * kt + 1];
                b.u[2] = hpk[4 * kt + 2]; b.u[3] = hpk[4 * kt + 3];
                acc = __builtin_amdgcn_mfma_f32_16x16x32_bf16(
                    *(const bf16x8*)(lds + M1_F + (mt * 4 + kt) * 1024 + lane * 16), b.v, acc, 0, 0, 0);
            }
            float mv[4];
            #pragma unroll
            for (int i = 0; i < 4; ++i) mv[i] = fmaxf(acc[i], 0.f);
            mpk[mt * 2]     = cvt_pk(mv[0], mv[1]);
            mpk[mt * 2 + 1] = cvt_pk(mv[2], mv[3]);
        }

        // ---- MLP2 [32x64] + MLP3 dot; B-frag(kt2) = mpk[4kt2..4kt2+3] ----
        float outacc = 0.f;
        #pragma unroll
        for (int mt = 0; mt < 2; ++mt) {
            const int r0 = mt * 16 + g * 4;             // m2 index (natural)
            f32x4 acc = *(const f32x4*)(bm2S + r0);     // bias as C-init
            #pragma unroll
            for (int kt = 0; kt < 2; ++kt) {
                union { uint32_t u[4]; bf16x8 v; } b;
                b.u[0] = mpk[4 * kt + 0]; b.u[1] = mpk[4 * kt + 1];
                b.u[2] = mpk[4 * kt + 2]; b.u[3] = mpk[4 * kt + 3];
                acc = __builtin_amdgcn_mfma_f32_16x16x32_bf16(
                    *(const bf16x8*)(lds + M2_F + (mt * 2 + kt) * 1024 + lane * 16), b.v, acc, 0, 0, 0);
            }
            f32x4 w3 = *(const f32x4*)(m3S + r0);
            #pragma unroll
            for (int i = 0; i < 4; ++i)
                outacc = fmaf(fmaxf(acc[i], 0.f), w3[i], outacc);
        }
        outacc += __shfl_xor(outacc, 16);
        outacc += __shfl_xor(outacc, 32);
        if (lane < 16) out[base + lane] = outacc + bm3v;
    }
}

extern "C" void kernel_launch(void* const* d_in, const int* in_sizes, int n_in,
                              void* d_out, int out_size, void* d_ws, size_t ws_size,
                              hipStream_t stream) {
    const float* x    = (const float*)d_in[0];
    // d_in[1] edge_index, d_in[2] edge_weight: dead (ChebConv K=1 on H=0)
    const float* W_i  = (const float*)d_in[3];
    // d_in[4] W_f: dead (multiplies C=0)
    const float* W_c  = (const float*)d_in[5];
    const float* W_o  = (const float*)d_in[6];
    // d_in[7..10] Uc_*: dead (H=0)
    const float* bc_i = (const float*)d_in[11];
    const float* bc_c = (const float*)d_in[13];
    const float* bc_o = (const float*)d_in[14];
    const float* w_co = (const float*)d_in[17];
    const float* b_i  = (const float*)d_in[18];
    const float* b_c  = (const float*)d_in[20];
    const float* b_o  = (const float*)d_in[21];
    const float* M1   = (const float*)d_in[22];
    const float* bm1  = (const float*)d_in[23];
    const float* M2   = (const float*)d_in[24];
    const float* bm2  = (const float*)d_in[25];
    const float* M3   = (const float*)d_in[26];
    const float* bm3  = (const float*)d_in[27];
    float* out = (float*)d_out;

    const int n = in_sizes[0] / IN_F;                   // 500000
    const int tiles = (n + 15) / 16;                    // 31250
    const int grid = (tiles + TILES_PER_BLOCK - 1) / TILES_PER_BLOCK;  // 489

    gclstm_mfma_kernel<<<grid, 1024, 0, stream>>>(
        x, W_i, W_c, W_o, bc_i, bc_c, bc_o, w_co,
        b_i, b_c, b_o, M1, bm1, M2, bm2, M3, bm3, out, n);
}